// Round 6
// baseline (184.847 us; speedup 1.0000x reference)
//
#include <hip/hip_runtime.h>
#include <stdint.h>

#define MB 8192
#define KD 256
#define BM 128            // rows per block: 4 waves x 32 rows (rt=2, proven reg shape)
#define BN 64             // cols per chunk
#define NSPLIT 32         // column slabs -> 2048 blocks (fine-grained rolling)
#define SLAB 256          // MB/NSPLIT
#define CHUNKS 4          // SLAB/BN
#define GRIDX 64          // MB/BM
#define LOG2E 1.44269504088896340736f
#define COFF 104.0f       // fixed exp offset: overflow/underflow-safe (verified R1-R5)
#define C2F (104.0f * 1.44269504088896340736f)

typedef __attribute__((ext_vector_type(8))) short bf16x8;
typedef __attribute__((ext_vector_type(4))) float f32x4;

union U8 { uint32_t u[4]; bf16x8 v; uint4 q; };

// (bf16_trunc(hi) << 16) | bf16_trunc(lo)  -- one v_perm_b32
__device__ __forceinline__ uint32_t pack2(float hi, float lo) {
  return __builtin_amdgcn_perm(__float_as_uint(hi), __float_as_uint(lo), 0x07060302);
}

__device__ __forceinline__ bf16x8 load_cvt8(const float* p) {
  float4 x = *(const float4*)p;
  float4 y = *(const float4*)(p + 4);
  U8 r;
  r.u[0] = pack2(x.y, x.x);
  r.u[1] = pack2(x.w, x.z);
  r.u[2] = pack2(y.y, y.x);
  r.u[3] = pack2(y.w, y.z);
  return r.v;
}

__device__ __forceinline__ float fast_exp2(float x) {
#if __has_builtin(__builtin_amdgcn_exp2f)
  return __builtin_amdgcn_exp2f(x);
#else
  return exp2f(x);
#endif
}

// ---- fused: inline-convert GEMM + masked fixed-offset exp-sum + match count
//      + diag fp32 pos + write-once partial slots (no atomics, no init) ----
__global__ __launch_bounds__(256, 3) void fused_kernel(
    const float* __restrict__ Af, const float* __restrict__ Bf,
    const int* __restrict__ ids, const float* __restrict__ q,
    float2* __restrict__ part, float* __restrict__ pos, float* __restrict__ out) {
  const int tid = threadIdx.x;
  const int wave = tid >> 6, lane = tid & 63, quad = lane >> 4, lpos = lane & 15;
  const int bx = blockIdx.x, by = blockIdx.y;
  const int rowbase = bx * BM + wave * 32;
  const int colbase = by * SLAB;

  if (bx == 0 && by == 0 && tid == 0) out[0] = 0.0f;   // finalize runs next dispatch

  // Fragment-ordered B staging: cell c = ct*512 + kb*64 + quad*16 + lpos at Bs+16c.
  // Frag reads lane-linear (lane i -> byte 16i): conflict-free ds_read_b128.
  __shared__ unsigned short Bs[2048 * 8];    // 32 KB

  // A fragments resident, converted inline from fp32 (truncation pack)
  bf16x8 afrag[2][8];
  #pragma unroll
  for (int rt = 0; rt < 2; ++rt)
    #pragma unroll
    for (int kb = 0; kb < 8; ++kb)
      afrag[rt][kb] = load_cvt8(Af + (size_t)(rowbase + rt * 16 + lpos) * KD + kb * 32 + quad * 8);

  int idr[2][4];
  float srun[2][4];
  int crun[2];                   // packed per-r byte counts of id-matches (max 16/lane)
  #pragma unroll
  for (int rt = 0; rt < 2; ++rt) {
    crun[rt] = 0;
    #pragma unroll
    for (int r = 0; r < 4; ++r) {
      idr[rt][r] = ids[rowbase + rt * 16 + quad * 4 + r];
      srun[rt][r] = 0.0f;
    }
  }

  // staging source (fp32): cell c = (2*ct+h)*256 + tid reads
  // Bf[(colbase + ct*16 + lp)*KD + (kb0 + 4h)*32 + qd*8 .. +8)
  const int lp = tid & 15, qd = (tid >> 4) & 3, kb0 = tid >> 6;
  const float* srcct[4];
  #pragma unroll
  for (int ct = 0; ct < 4; ++ct)
    srcct[ct] = Bf + (size_t)(colbase + ct * 16 + lp) * KD + kb0 * 32 + qd * 8;

  for (int ch = 0; ch < CHUNKS; ++ch) {
    __syncthreads();                         // Bs safe to overwrite
    #pragma unroll
    for (int ct = 0; ct < 4; ++ct) {
      #pragma unroll
      for (int h = 0; h < 2; ++h) {
        const float* src = srcct[ct] + h * 128;
        float4 x = *(const float4*)src;
        float4 y = *(const float4*)(src + 4);
        U8 r;
        r.u[0] = pack2(x.y, x.x);
        r.u[1] = pack2(x.w, x.z);
        r.u[2] = pack2(y.y, y.x);
        r.u[3] = pack2(y.w, y.z);
        *((uint4*)Bs + (2 * ct + h) * 256 + tid) = r.q;
      }
      srcct[ct] += BN * KD;                  // advance to next chunk
    }
    __syncthreads();                         // staging visible

    const int colchunk = colbase + ch * BN;
    #pragma unroll
    for (int ct = 0; ct < 4; ++ct) {
      bf16x8 bfrag[8];
      #pragma unroll
      for (int kb = 0; kb < 8; ++kb)
        bfrag[kb] = *(const bf16x8*)(Bs + (size_t)(ct * 512 + kb * 64 + quad * 16 + lpos) * 8);
      f32x4 acc[2] = {{0,0,0,0},{0,0,0,0}};
      #pragma unroll
      for (int kb = 0; kb < 8; ++kb)
        #pragma unroll
        for (int rt = 0; rt < 2; ++rt)       // 2 independent chains
          acc[rt] = __builtin_amdgcn_mfma_f32_16x16x32_bf16(afrag[rt][kb], bfrag[kb], acc[rt], 0, 0, 0);
      const int j = colchunk + ct * 16 + lpos;
      const int idj = ids[j];
      const float b2j = -__log2f(q[j]) - C2F;   // -log2(q_j) - C*log2e
      #pragma unroll
      for (int rt = 0; rt < 2; ++rt)
        #pragma unroll
        for (int r = 0; r < 4; ++r) {
          const bool match = (idj == idr[rt][r]);
          const float x = fmaf(acc[rt][r], LOG2E, b2j);
          srun[rt][r] += fast_exp2(match ? -1000.0f : x);   // exp2(-1000)=0
          crun[rt] += match ? (1 << (8 * r)) : 0;
        }
    }
  }

  // reduce (s, matches) across the 16 lpos lanes; one write-once slot per (slab,row)
  #pragma unroll
  for (int rt = 0; rt < 2; ++rt)
    #pragma unroll
    for (int r = 0; r < 4; ++r) {
      float s = srun[rt][r];
      float c = (float)((crun[rt] >> (8 * r)) & 255);
      #pragma unroll
      for (int off = 1; off < 16; off <<= 1) {
        s += __shfl_xor(s, off, 64);
        c += __shfl_xor(c, off, 64);
      }
      if (lpos == 0) {
        const int gi = rowbase + rt * 16 + quad * 4 + r;
        part[(size_t)by * MB + gi] = make_float2(s, c);
      }
    }

  // ---- diagonal blocks: fp32 pos_sim for their 128 rows ----
  if (by == (bx >> 1)) {
    const int i = bx * BM + (tid >> 1);
    const int hh = tid & 1;
    const float* ap = Af + (size_t)i * KD + hh * 128;
    const float* bp = Bf + (size_t)i * KD + hh * 128;
    float d = 0.0f;
    #pragma unroll 4
    for (int k = 0; k < 32; ++k) {
      float4 a = ((const float4*)ap)[k];
      float4 b = ((const float4*)bp)[k];
      d += a.x * b.x + a.y * b.y + a.z * b.z + a.w * b.w;
    }
    d += __shfl_xor(d, 1, 64);
    if (hh == 0) pos[i] = d;
  }
}

// ---- finalize: merge slab partials, per-row loss, mean ----
__global__ __launch_bounds__(256) void finalize_kernel(
    const float2* __restrict__ part, const float* __restrict__ pos,
    const float* __restrict__ q, float* __restrict__ out) {
  int i = blockIdx.x * 256 + threadIdx.x;   // 32 blocks -> 8192 threads
  float s = 0.0f, c = 0.0f;
  #pragma unroll
  for (int y = 0; y < NSPLIT; ++y) {
    float2 v = part[(size_t)y * MB + i];
    s += v.x; c += v.y;
  }
  const float nm = (float)MB - c;           // n_miss
  const float z = logf(s) + COFF + log1pf(-q[i]) - logf(nm);
  const float p = pos[i];
  const float hi = fmaxf(p, z), lo = fminf(p, z);
  float loss = -p + hi + log1pf(__expf(lo - hi));

  #pragma unroll
  for (int off = 32; off; off >>= 1) loss += __shfl_down(loss, off, 64);
  __shared__ float red[4];
  if ((threadIdx.x & 63) == 0) red[threadIdx.x >> 6] = loss;
  __syncthreads();
  if (threadIdx.x == 0) {
    float t = red[0] + red[1] + red[2] + red[3];
    atomicAdd(out, t * (1.0f / (float)MB));
  }
}

extern "C" void kernel_launch(void* const* d_in, const int* in_sizes, int n_in,
                              void* d_out, int out_size, void* d_ws, size_t ws_size,
                              hipStream_t stream) {
  (void)in_sizes; (void)n_in; (void)out_size; (void)ws_size;
  const float* input_emb  = (const float*)d_in[0];
  const float* target_emb = (const float*)d_in[1];
  const int*   target_ids = (const int*)d_in[2];
  const float* q_probas   = (const float*)d_in[3];
  float* out = (float*)d_out;

  char* ws = (char*)d_ws;
  float2* part = (float2*)ws;                       // 32*8192*8 = 2 MB
  float*  pos  = (float*)(ws + (2u << 20));         // 32 KB

  fused_kernel<<<dim3(GRIDX, NSPLIT), 256, 0, stream>>>(
      input_emb, target_emb, target_ids, q_probas, part, pos, out);
  finalize_kernel<<<32, 256, 0, stream>>>(part, pos, q_probas, out);
}

// Round 7
// 136.956 us; speedup vs baseline: 1.3497x; 1.3497x over previous
//
#include <hip/hip_runtime.h>
#include <stdint.h>

#define MB 8192
#define KD 256
#define BM 128            // rows per block: 4 waves x 32 rows (rt=2, proven VGPR=84 shape)
#define BN 64             // cols per chunk
#define NSPLIT 16         // column slabs -> 1024 blocks, 3 resident/CU at (256,3)
#define SLAB 512          // MB/NSPLIT
#define CHUNKS 8          // SLAB/BN
#define GRIDX 64          // MB/BM
#define COFF 104.0f       // fixed exp offset: overflow/underflow-safe (verified R1-R6)
#define LOG2E 1.44269504088896340736f

typedef __attribute__((ext_vector_type(8))) short bf16x8;
typedef __attribute__((ext_vector_type(4))) float f32x4;

typedef const __attribute__((address_space(1))) uint32_t* gptr_t;
typedef __attribute__((address_space(3))) uint32_t* lptr_t;

__device__ __forceinline__ unsigned short f2bf(float x) {
  union { float f; uint32_t u; } v; v.f = x;
  uint32_t r = v.u + 0x7fffu + ((v.u >> 16) & 1u);   // RNE
  return (unsigned short)(r >> 16);
}

__device__ __forceinline__ float fast_exp2(float x) {
#if __has_builtin(__builtin_amdgcn_exp2f)
  return __builtin_amdgcn_exp2f(x);
#else
  return exp2f(x);
#endif
}

// ---- prep: fp32->bf16 A,B (RNE); pos_sim; b2 = (-log q - C)*log2e ----
__global__ __launch_bounds__(256) void prep_kernel(
    const float* __restrict__ A, const float* __restrict__ B,
    const float* __restrict__ q,
    unsigned short* __restrict__ Abf, unsigned short* __restrict__ Bbf,
    float* __restrict__ b2, float* __restrict__ pos) {
  int t = blockIdx.x * 256 + threadIdx.x;        // 524288 threads, 1 float4 each
  const float4 a = ((const float4*)A)[t];
  const float4 b = ((const float4*)B)[t];
  ushort4 oa, ob;
  oa.x = f2bf(a.x); oa.y = f2bf(a.y); oa.z = f2bf(a.z); oa.w = f2bf(a.w);
  ob.x = f2bf(b.x); ob.y = f2bf(b.y); ob.z = f2bf(b.z); ob.w = f2bf(b.w);
  ((ushort4*)Abf)[t] = oa;
  ((ushort4*)Bbf)[t] = ob;
  // pos_sim: wave (t>>6) == row
  float d = a.x * b.x + a.y * b.y + a.z * b.z + a.w * b.w;
  #pragma unroll
  for (int off = 32; off; off >>= 1) d += __shfl_down(d, off, 64);
  if ((threadIdx.x & 63) == 0) pos[t >> 6] = d;
  if (t < MB) b2[t] = (-logf(q[t]) - COFF) * LOG2E;
}

// ---- fused GEMM + masked fixed-offset exp-sum + match count ----
// No fences, no atomics: write-once partial slots part[y][row].
__global__ __launch_bounds__(256, 3) void fused_kernel(
    const unsigned short* __restrict__ Abf,
    const unsigned short* __restrict__ Bbf,
    const int* __restrict__ ids,
    const float* __restrict__ b2,
    float2* __restrict__ part) {
  const int tid = threadIdx.x;
  const int wave = tid >> 6, lane = tid & 63, quad = lane >> 4, lpos = lane & 15;
  const int rowbase = blockIdx.x * BM + wave * 32;
  const int colbase = blockIdx.y * SLAB;

  // Fragment-ordered B staging: cell c = ct*512 + kb*64 + quad*16 + lpos at Bs+16c.
  // Frag reads are lane-linear (lane i -> byte 16i): conflict-free ds_read_b128.
  // Staging dest c = tid + s8*256 is lane-linear too -> global_load_lds legal.
  __shared__ unsigned short Bs[2048 * 8];    // 32 KB

  // A fragments resident: wave owns rows [rowbase, rowbase+32)  (64 VGPRs)
  bf16x8 afrag[2][8];
  #pragma unroll
  for (int rt = 0; rt < 2; ++rt)
    #pragma unroll
    for (int kb = 0; kb < 8; ++kb)
      afrag[rt][kb] = *(const bf16x8*)(Abf + (size_t)(rowbase + rt * 16 + lpos) * KD + kb * 32 + quad * 8);

  int idr[2][4];
  float srun[2][4];
  int crun[2];                   // packed per-r byte counts of id-matches (max 32/lane: safe)
  #pragma unroll
  for (int rt = 0; rt < 2; ++rt) {
    crun[rt] = 0;
    #pragma unroll
    for (int r = 0; r < 4; ++r) {
      idr[rt][r] = ids[rowbase + rt * 16 + quad * 4 + r];
      srun[rt][r] = 0.0f;
    }
  }

  // staging sources: s8 = 2*ct + h; cell c = tid + s8*256 reads
  // Bbf[(colbase + ct*16 + lp)*KD + (kb0 + 4h)*32 + qd*8]
  const int lp = tid & 15, qd = (tid >> 4) & 3, kb0 = (tid >> 6) & 3;
  const unsigned short* srcct[4];
  #pragma unroll
  for (int ct = 0; ct < 4; ++ct)
    srcct[ct] = Bbf + (size_t)(colbase + ct * 16 + lp) * KD + kb0 * 32 + qd * 8;

  for (int ch = 0; ch < CHUNKS; ++ch) {
    __syncthreads();                         // Bs safe to overwrite
    #pragma unroll
    for (int ct = 0; ct < 4; ++ct) {
      #pragma unroll
      for (int h = 0; h < 2; ++h) {
        const int s8 = ct * 2 + h;
        __builtin_amdgcn_global_load_lds(
            (gptr_t)(const void*)(srcct[ct] + h * 128),
            (lptr_t)(void*)(Bs + (size_t)(tid + s8 * 256) * 8),
            16, 0, 0);
      }
      srcct[ct] += BN * KD;                  // advance to next chunk
    }
    __syncthreads();                         // loads landed

    const int colchunk = colbase + ch * BN;
    #pragma unroll
    for (int ct = 0; ct < 4; ++ct) {
      bf16x8 bfrag[8];
      #pragma unroll
      for (int kb = 0; kb < 8; ++kb)
        bfrag[kb] = *(const bf16x8*)(Bs + (size_t)(ct * 512 + kb * 64 + quad * 16 + lpos) * 8);
      f32x4 acc[2] = {{0,0,0,0},{0,0,0,0}};
      #pragma unroll
      for (int kb = 0; kb < 8; ++kb)
        #pragma unroll
        for (int rt = 0; rt < 2; ++rt)       // 2 independent chains
          acc[rt] = __builtin_amdgcn_mfma_f32_16x16x32_bf16(afrag[rt][kb], bfrag[kb], acc[rt], 0, 0, 0);
      const int j = colchunk + ct * 16 + lpos;
      const int idj = ids[j];
      const float bj = b2[j];
      #pragma unroll
      for (int rt = 0; rt < 2; ++rt)
        #pragma unroll
        for (int r = 0; r < 4; ++r) {
          const bool match = (idj == idr[rt][r]);
          const float x = fmaf(acc[rt][r], LOG2E, bj);
          srun[rt][r] += fast_exp2(match ? -1000.0f : x);   // exp2(-1000)=0
          crun[rt] += match ? (1 << (8 * r)) : 0;
        }
    }
  }

  // reduce (s, matches) across the 16 lpos lanes of each quad; write-once slot
  #pragma unroll
  for (int rt = 0; rt < 2; ++rt)
    #pragma unroll
    for (int r = 0; r < 4; ++r) {
      float s = srun[rt][r];
      float c = (float)((crun[rt] >> (8 * r)) & 255);
      #pragma unroll
      for (int off = 1; off < 16; off <<= 1) {
        s += __shfl_xor(s, off, 64);
        c += __shfl_xor(c, off, 64);
      }
      if (lpos == 0) {
        const int gi = rowbase + rt * 16 + quad * 4 + r;
        part[(size_t)blockIdx.y * MB + gi] = make_float2(s, c);
      }
    }
}

// ---- finalize: merge slab partials, per-row loss, mean ----
__global__ __launch_bounds__(256) void finalize_kernel(
    const float2* __restrict__ part, const float* __restrict__ pos,
    const float* __restrict__ q, float* __restrict__ out) {
  int i = blockIdx.x * 256 + threadIdx.x;   // 32 blocks -> 8192 threads
  float s = 0.0f, c = 0.0f;
  #pragma unroll
  for (int y = 0; y < NSPLIT; ++y) {
    float2 v = part[(size_t)y * MB + i];
    s += v.x; c += v.y;
  }
  const float nm = (float)MB - c;           // n_miss
  const float z = logf(s) + COFF + log1pf(-q[i]) - logf(nm);
  const float p = pos[i];
  const float hi = fmaxf(p, z), lo = fminf(p, z);
  float loss = -p + hi + log1pf(__expf(lo - hi));

  #pragma unroll
  for (int off = 32; off; off >>= 1) loss += __shfl_down(loss, off, 64);
  __shared__ float red[4];
  if ((threadIdx.x & 63) == 0) red[threadIdx.x >> 6] = loss;
  __syncthreads();
  if (threadIdx.x == 0) {
    float t = red[0] + red[1] + red[2] + red[3];
    atomicAdd(out, t * (1.0f / (float)MB));
  }
}

extern "C" void kernel_launch(void* const* d_in, const int* in_sizes, int n_in,
                              void* d_out, int out_size, void* d_ws, size_t ws_size,
                              hipStream_t stream) {
  (void)in_sizes; (void)n_in; (void)out_size; (void)ws_size;
  const float* input_emb  = (const float*)d_in[0];
  const float* target_emb = (const float*)d_in[1];
  const int*   target_ids = (const int*)d_in[2];
  const float* q_probas   = (const float*)d_in[3];
  float* out = (float*)d_out;

  char* ws = (char*)d_ws;
  unsigned short* Abf = (unsigned short*)(ws);                    // 4 MB
  unsigned short* Bbf = (unsigned short*)(ws + (4u << 20));       // 4 MB
  float2* part = (float2*)(ws + (8u << 20));                      // 16*8192*8 = 1 MB
  float*  b2   = (float*)(ws + (9u << 20));                       // 32 KB
  float*  pos  = (float*)(ws + (9u << 20) + 32768);               // 32 KB

  hipMemsetAsync(out, 0, sizeof(float), stream);
  prep_kernel<<<2048, 256, 0, stream>>>(input_emb, target_emb, q_probas,
                                        Abf, Bbf, b2, pos);
  fused_kernel<<<dim3(GRIDX, NSPLIT), 256, 0, stream>>>(
      Abf, Bbf, target_ids, b2, part);
  finalize_kernel<<<32, 256, 0, stream>>>(part, pos, q_probas, out);
}